// Round 1
// baseline (809.409 us; speedup 1.0000x reference)
//
#include <hip/hip_runtime.h>
#include <math.h>

// Problem constants (from reference):
//   N=131072 rows, INPT_DIM=128, output labels = argmin_k ||c1_k||^2 - 2*x.c1_k
//   where x = inpt[:, 64:128], centers1 shape (1024, 64). centers0 unused.
constexpr int N_ROWS   = 131072;
constexpr int INPT_DIM = 128;
constexpr int DIM      = 64;     // slice width (second slice)
constexpr int COL_OFF  = 64;     // offset of second slice
constexpr int NCENT    = 1024;

// ---------------------------------------------------------------------------
// Kernel 1: per-center squared norms, in f64 (exact path) and f32 (fast path).
// d_ws is re-poisoned before every launch, so this runs every kernel_launch.
// ---------------------------------------------------------------------------
__global__ void cnorm_kernel(const float* __restrict__ centers,
                             double* __restrict__ cnorm_d,
                             float* __restrict__ cnorm_f) {
    int k = blockIdx.x * blockDim.x + threadIdx.x;
    if (k >= NCENT) return;
    const float* c = centers + (size_t)k * DIM;
    double sd = 0.0;
#pragma unroll 8
    for (int d = 0; d < DIM; ++d) {
        double cd = (double)c[d];
        sd = fma(cd, cd, sd);
    }
    cnorm_d[k] = sd;
    cnorm_f[k] = (float)sd;
}

// ---------------------------------------------------------------------------
// Kernel 2: one thread per row. fp32 dot products vs all 1024 centers with
// top-2 (value, index) tracking; if the top-2 gap is below eps (covers the
// worst-case fp32 rounding of a 64-term dot, ~6e-4), rescore the two
// candidates in exact f64 with first-index tie-break (matches jnp.argmin).
// ---------------------------------------------------------------------------
__device__ __forceinline__ double exact_score(const float* __restrict__ c,
                                              const float x[DIM], double cn) {
    double acc = 0.0;
#pragma unroll
    for (int d = 0; d < DIM; ++d)
        acc = fma((double)c[d], (double)x[d], acc);
    return fma(-2.0, acc, cn);
}

__launch_bounds__(256)
__global__ void label_kernel(const float* __restrict__ inpt,
                             const float* __restrict__ centers,
                             const double* __restrict__ cnorm_d,
                             const float* __restrict__ cnorm_f,
                             int* __restrict__ out) {
    int row = blockIdx.x * blockDim.x + threadIdx.x;
    if (row >= N_ROWS) return;

    // Load this row's 64-wide slice into registers (fully unrolled -> VGPRs).
    const float* xr = inpt + (size_t)row * INPT_DIM + COL_OFF;
    float x[DIM];
#pragma unroll
    for (int d = 0; d < DIM; d += 4) {
        float4 v = *reinterpret_cast<const float4*>(xr + d);
        x[d] = v.x; x[d + 1] = v.y; x[d + 2] = v.z; x[d + 3] = v.w;
    }

    float min1 = INFINITY, min2 = INFINITY;
    int arg1 = 0, arg2 = 0;

    // 4 centers per iteration for ILP; center addresses are wave-uniform so
    // the compiler can scalarize these loads (s_load) — centers stay in L2.
    for (int k = 0; k < NCENT; k += 4) {
        const float* c = centers + (size_t)k * DIM;
        float a0 = 0.f, a1 = 0.f, a2 = 0.f, a3 = 0.f;
#pragma unroll
        for (int d = 0; d < DIM; ++d) {
            float xd = x[d];
            a0 = fmaf(c[d],            xd, a0);
            a1 = fmaf(c[DIM + d],      xd, a1);
            a2 = fmaf(c[2 * DIM + d],  xd, a2);
            a3 = fmaf(c[3 * DIM + d],  xd, a3);
        }
        float s0 = fmaf(-2.f, a0, cnorm_f[k]);
        float s1 = fmaf(-2.f, a1, cnorm_f[k + 1]);
        float s2 = fmaf(-2.f, a2, cnorm_f[k + 2]);
        float s3 = fmaf(-2.f, a3, cnorm_f[k + 3]);

        // Sequential (ascending-k) top-2 update preserves first-min semantics.
        if (s0 < min1) { min2 = min1; arg2 = arg1; min1 = s0; arg1 = k; }
        else if (s0 < min2) { min2 = s0; arg2 = k; }
        if (s1 < min1) { min2 = min1; arg2 = arg1; min1 = s1; arg1 = k + 1; }
        else if (s1 < min2) { min2 = s1; arg2 = k + 1; }
        if (s2 < min1) { min2 = min1; arg2 = arg1; min1 = s2; arg1 = k + 2; }
        else if (s2 < min2) { min2 = s2; arg2 = k + 2; }
        if (s3 < min1) { min2 = min1; arg2 = arg1; min1 = s3; arg1 = k + 3; }
        else if (s3 < min2) { min2 = s3; arg2 = k + 3; }
    }

    int result = arg1;
    // fp32 worst-case score error is ~6e-4 here; 2e-3 gap is decisive.
    if (min2 - min1 < 2.0e-3f) {
        double e1 = exact_score(centers + (size_t)arg1 * DIM, x, cnorm_d[arg1]);
        double e2 = exact_score(centers + (size_t)arg2 * DIM, x, cnorm_d[arg2]);
        if (e2 < e1 || (e2 == e1 && arg2 < arg1)) result = arg2;
    }
    out[row] = result;
}

// ---------------------------------------------------------------------------
extern "C" void kernel_launch(void* const* d_in, const int* in_sizes, int n_in,
                              void* d_out, int out_size, void* d_ws, size_t ws_size,
                              hipStream_t stream) {
    const float* inpt     = (const float*)d_in[0];
    // d_in[1] = centers0 — unused (reference returns last slice's labels only)
    const float* centers1 = (const float*)d_in[2];
    int* out = (int*)d_out;

    // Workspace layout: [0, 8K) f64 cnorm, [8K, 12K) f32 cnorm.
    double* cnorm_d = (double*)d_ws;
    float*  cnorm_f = (float*)((char*)d_ws + NCENT * sizeof(double));

    cnorm_kernel<<<(NCENT + 255) / 256, 256, 0, stream>>>(centers1, cnorm_d, cnorm_f);
    label_kernel<<<N_ROWS / 256, 256, 0, stream>>>(inpt, centers1, cnorm_d, cnorm_f, out);
}